// Round 2
// baseline (239.405 us; speedup 1.0000x reference)
//
#include <hip/hip_runtime.h>

typedef unsigned short u16;
typedef __attribute__((ext_vector_type(4))) unsigned short u16x4;
typedef __attribute__((ext_vector_type(8))) short short8;
typedef __attribute__((ext_vector_type(4))) float floatx4;

#define NB 8192        // rows
#define DK 1024        // D_IN
#define DN 1024        // D_OUT
#define NE 16          // experts
#define TM 128
#define TN 128
#define BK 64
#define MAX_TILES 80   // sum ceil(cnt_e/128) <= 64 + 16

#define GATE_BLOCKS 256          // 32 rows each
#define WET_BLOCKS  4096         // 16 e * 16 n-tiles * 16 k-tiles (64x64)

__device__ __forceinline__ u16 f2bf(float f) {
    union { float f; unsigned int u; } v; v.f = f;
    unsigned int u = v.u;
    return (u16)((u + 0x7fffu + ((u >> 16) & 1u)) >> 16);
}

__device__ __forceinline__ void gld16(const void* g, void* l) {
    __builtin_amdgcn_global_load_lds(
        (const __attribute__((address_space(1))) unsigned int*)g,
        (__attribute__((address_space(3))) unsigned int*)l, 16, 0, 0);
}

// ---------------- K1: fused gate (fp64, register-blocked) + x->bf16 + We transpose ----------------
__global__ __launch_bounds__(256) void k_prep(const float* __restrict__ x,
                                              const float* __restrict__ Wg,
                                              const float* __restrict__ bg,
                                              const float* __restrict__ We,
                                              u16* __restrict__ xb,
                                              u16* __restrict__ WeT,
                                              int* __restrict__ cnt,
                                              int* __restrict__ bucket) {
    __shared__ union {
        struct { float xs[32 * 132]; float wgs[16 * 132]; } g;  // 25344 B
        u16 t[64 * 68];                                         //  8704 B
    } sh;

    const int tid = threadIdx.x;

    if (blockIdx.x < GATE_BLOCKS) {
        // ---- gate branch: 32 rows, 16 experts, fp64 accumulate ----
        // tid = rg*32 + eg*8 + kg : kg = k-split(8), eg = expert group(4), rg = row group(8)
        const int kg = tid & 7;
        const int eg = (tid >> 3) & 3;
        const int rg = tid >> 5;
        const int R0 = blockIdx.x * 32;

        float* xs  = sh.g.xs;   // [32][132]
        float* wgs = sh.g.wgs;  // [16][132]

        double acc[4][4];
        #pragma unroll
        for (int i = 0; i < 4; ++i)
            #pragma unroll
            for (int j = 0; j < 4; ++j) acc[i][j] = 0.0;

        for (int c = 0; c < 8; ++c) {
            const int k0 = c * 128;
            // stage x chunk [32][128] fp32 + emit bf16 copy
            #pragma unroll
            for (int it = 0; it < 4; ++it) {
                int f = it * 256 + tid;
                int r = f >> 5;
                int k4 = (f & 31) * 4;
                float4 v = *(const float4*)&x[(size_t)(R0 + r) * DK + k0 + k4];
                *(float4*)&xs[r * 132 + k4] = v;
                u16x4 b; b.x = f2bf(v.x); b.y = f2bf(v.y); b.z = f2bf(v.z); b.w = f2bf(v.w);
                *(u16x4*)&xb[(size_t)(R0 + r) * DK + k0 + k4] = b;
            }
            // stage Wg chunk transposed: wgs[e][k]
            #pragma unroll
            for (int it = 0; it < 2; ++it) {
                int g = it * 256 + tid;
                int k = g >> 2;
                int e4 = (g & 3) * 4;
                float4 v = *(const float4*)&Wg[(size_t)(k0 + k) * NE + e4];
                wgs[(e4 + 0) * 132 + k] = v.x;
                wgs[(e4 + 1) * 132 + k] = v.y;
                wgs[(e4 + 2) * 132 + k] = v.z;
                wgs[(e4 + 3) * 132 + k] = v.w;
            }
            __syncthreads();
            // 16 k per thread, interleaved so kg*4 word offsets spread banks
            #pragma unroll
            for (int t = 0; t < 4; ++t) {
                const int ko = t * 32 + kg * 4;
                float4 xq[4], wq[4];
                #pragma unroll
                for (int i = 0; i < 4; ++i)
                    xq[i] = *(const float4*)&xs[(rg * 4 + i) * 132 + ko];
                #pragma unroll
                for (int j = 0; j < 4; ++j)
                    wq[j] = *(const float4*)&wgs[(eg * 4 + j) * 132 + ko];
                #pragma unroll
                for (int i = 0; i < 4; ++i)
                    #pragma unroll
                    for (int j = 0; j < 4; ++j) {
                        acc[i][j] += (double)xq[i].x * (double)wq[j].x;
                        acc[i][j] += (double)xq[i].y * (double)wq[j].y;
                        acc[i][j] += (double)xq[i].z * (double)wq[j].z;
                        acc[i][j] += (double)xq[i].w * (double)wq[j].w;
                    }
            }
            __syncthreads();
        }

        // k-split reduction across kg (lanes xor 1,2,4) + bias
        #pragma unroll
        for (int i = 0; i < 4; ++i)
            #pragma unroll
            for (int j = 0; j < 4; ++j) {
                double v = acc[i][j];
                v += __shfl_xor(v, 1);
                v += __shfl_xor(v, 2);
                v += __shfl_xor(v, 4);
                acc[i][j] = v + (double)bg[eg * 4 + j];
            }

        // per-row argmax (first-max wins, matching np.argmax)
        #pragma unroll
        for (int i = 0; i < 4; ++i) {
            double best = acc[i][0]; int bi = eg * 4;
            #pragma unroll
            for (int j = 1; j < 4; ++j)
                if (acc[i][j] > best) { best = acc[i][j]; bi = eg * 4 + j; }
            #pragma unroll
            for (int off = 8; off <= 16; off <<= 1) {
                double ov = __shfl_xor(best, off);
                int    oi = __shfl_xor(bi, off);
                if (ov > best || (ov == best && oi < bi)) { best = ov; bi = oi; }
            }
            if (kg == 0 && eg == 0) {
                int pos = atomicAdd(&cnt[bi], 1);
                bucket[bi * NB + pos] = R0 + rg * 4 + i;
            }
        }
    } else {
        // ---- transpose branch: We fp32 [E][K][N] -> bf16 [E][N][K], 64x64 tile ----
        const int bw = blockIdx.x - GATE_BLOCKS;
        const int e  = bw >> 8;
        const int n0 = ((bw >> 4) & 15) * 64;
        const int k0 = (bw & 15) * 64;
        u16* t = sh.t;
        const float* src = We + (size_t)e * DK * DN;
        const int kl = tid >> 4;
        const int n4 = (tid & 15) * 4;
        #pragma unroll
        for (int r = 0; r < 4; ++r) {
            int k = kl + r * 16;
            float4 v = *(const float4*)&src[(size_t)(k0 + k) * DN + n0 + n4];
            t[(n4 + 0) * 68 + k] = f2bf(v.x);
            t[(n4 + 1) * 68 + k] = f2bf(v.y);
            t[(n4 + 2) * 68 + k] = f2bf(v.z);
            t[(n4 + 3) * 68 + k] = f2bf(v.w);
        }
        __syncthreads();
        u16* dst = WeT + (size_t)e * DN * DK;
        #pragma unroll
        for (int r = 0; r < 4; ++r) {
            int c = r * 256 + tid;
            int nl = c >> 4;
            int kq = (c & 15) * 4;
            *(u16x4*)&dst[(size_t)(n0 + nl) * DK + k0 + kq] = *(const u16x4*)&t[nl * 68 + kq];
        }
    }
}

// ---------------- K3: grouped GEMM, bf16 MFMA 16x16x32, 128x128 tile ----------------
__global__ __launch_bounds__(256) void k_moe(const u16* __restrict__ xb,
                                             const u16* __restrict__ WeT,
                                             const float* __restrict__ be,
                                             const int* __restrict__ bucket,
                                             const int* __restrict__ cnt,
                                             float* __restrict__ out) {
    const int slot = blockIdx.x >> 3;
    const int nt = blockIdx.x & 7;

    // inline tile-list: map slot -> (expert e, m-tile mt)
    int e = -1, mt = 0, cntE = 0, acc_t = 0;
    #pragma unroll
    for (int ee = 0; ee < NE; ++ee) {
        int ce = cnt[ee];
        int nte = (ce + TM - 1) / TM;
        if (e < 0 && slot < acc_t + nte) { e = ee; mt = slot - acc_t; cntE = ce; }
        acc_t += nte;
    }
    if (e < 0) return;

    const int m0 = mt * TM;
    const int n0 = nt * TN;

    __shared__ u16 aLds[TM * BK];  // 16 KB, xor-swizzled k-slots
    __shared__ u16 bLds[TN * BK];  // 16 KB

    const int tid = threadIdx.x;
    const int lane = tid & 63;
    const int w = tid >> 6;
    const int wr = w >> 1, wc = w & 1;
    const int lr = lane & 15, q = lane >> 4;

    // staging addresses: chunk c -> (row = c/8, stored slot = c%8, global k8 = slot ^ (row&7))
    long aoff[4]; long boff[4]; int ldsb[4];
    #pragma unroll
    for (int r = 0; r < 4; ++r) {
        int c = r * 256 + tid;
        int row = c >> 3;
        int k8 = (c & 7) ^ (row & 7);
        int m_idx = m0 + row; if (m_idx >= cntE) m_idx = cntE - 1;
        long rid = bucket[e * NB + m_idx];
        aoff[r] = rid * DK + k8 * 8;
        boff[r] = (long)e * DN * DK + (long)(n0 + row) * DK + k8 * 8;
        ldsb[r] = (r * 256 + (tid & ~63)) * 8;  // ushort elements (16B per chunk)
    }

    floatx4 acc[4][4];
    #pragma unroll
    for (int mi = 0; mi < 4; ++mi)
        #pragma unroll
        for (int ni = 0; ni < 4; ++ni)
            acc[mi][ni] = (floatx4)0.0f;

    for (int kk = 0; kk < DK; kk += BK) {
        #pragma unroll
        for (int r = 0; r < 4; ++r) {
            gld16(xb + aoff[r] + kk, &aLds[ldsb[r]]);
            gld16(WeT + boff[r] + kk, &bLds[ldsb[r]]);
        }
        __syncthreads();
        #pragma unroll
        for (int ks = 0; ks < 2; ++ks) {
            short8 af[4], bfr[4];
            const int slot_k = ((ks << 2) + q) ^ (lr & 7);
            #pragma unroll
            for (int mi = 0; mi < 4; ++mi) {
                int row = wr * 64 + mi * 16 + lr;
                af[mi] = *(const short8*)&aLds[row * BK + slot_k * 8];
                int nrow = wc * 64 + mi * 16 + lr;
                bfr[mi] = *(const short8*)&bLds[nrow * BK + slot_k * 8];
            }
            #pragma unroll
            for (int mi = 0; mi < 4; ++mi)
                #pragma unroll
                for (int ni = 0; ni < 4; ++ni)
                    acc[mi][ni] = __builtin_amdgcn_mfma_f32_16x16x32_bf16(
                        af[mi], bfr[ni], acc[mi][ni], 0, 0, 0);
        }
        __syncthreads();
    }

    // epilogue: C/D layout col = lane&15, row = q*4 + reg
    float bias[4];
    #pragma unroll
    for (int ni = 0; ni < 4; ++ni)
        bias[ni] = be[e * DN + n0 + wc * 64 + ni * 16 + lr];

    #pragma unroll
    for (int mi = 0; mi < 4; ++mi) {
        #pragma unroll
        for (int rr = 0; rr < 4; ++rr) {
            int row_l = wr * 64 + mi * 16 + q * 4 + rr;
            int m_idx = m0 + row_l;
            if (m_idx < cntE) {
                long rid = bucket[e * NB + m_idx];
                float* orow = out + rid * DN + n0 + wc * 64 + lr;
                #pragma unroll
                for (int ni = 0; ni < 4; ++ni)
                    orow[ni * 16] = acc[mi][ni][rr] + bias[ni];
            }
        }
    }
}

extern "C" void kernel_launch(void* const* d_in, const int* in_sizes, int n_in,
                              void* d_out, int out_size, void* d_ws, size_t ws_size,
                              hipStream_t stream) {
    const float* x  = (const float*)d_in[0];
    const float* Wg = (const float*)d_in[1];
    const float* bg = (const float*)d_in[2];
    const float* We = (const float*)d_in[3];
    const float* be = (const float*)d_in[4];
    float* out = (float*)d_out;

    int* cnt    = (int*)d_ws;           // 16 ints
    int* bucket = cnt + 128;            // 16*8192 ints
    u16* xb  = (u16*)((char*)d_ws + (1u << 20));    // 16 MB @ 1MB
    u16* wet = (u16*)((char*)d_ws + (18u << 20));   // 32 MB @ 18MB

    hipMemsetAsync(cnt, 0, 16 * sizeof(int), stream);
    k_prep<<<GATE_BLOCKS + WET_BLOCKS, 256, 0, stream>>>(x, Wg, bg, We, xb, wet, cnt, bucket);
    k_moe<<<MAX_TILES * 8, 256, 0, stream>>>(xb, wet, be, bucket, cnt, out);
}